// Round 5
// baseline (700.798 us; speedup 1.0000x reference)
//
#include <hip/hip_runtime.h>
#include <math.h>

// Problem constants (match reference)
#define BATCH 16
#define NPTS  8192
#define FEATC 384
#define NG    512
#define KM    32

// d_out layout (flat float32, concatenated in return order)
#define OUT0_OFF 0                              // neighborhood [16,512,32,3]
#define OUT1_OFF (BATCH * NG * KM * 3)          // center       [16,512,3]
#define OUT2_OFF (OUT1_OFF + BATCH * NG * 3)    // feature_group[16,512,32,384]

// Disable FP contraction so mul/add rounding matches the numpy reference.
#pragma clang fp contract(off)

typedef float f32x2 __attribute__((ext_vector_type(2)));

// ---------------------------------------------------------------------------
// DPP wave64 reductions, all-VALU. row_shr:1/2/4/8 fold each 16-lane row into
// its top lane; row_bcast:15/31 fold rows. Result valid in lane 63.
// ---------------------------------------------------------------------------
template <int CTRL>
__device__ __forceinline__ unsigned long long dpp_u64(unsigned long long k) {
    unsigned lo = (unsigned)k, hi = (unsigned)(k >> 32);
    lo = (unsigned)__builtin_amdgcn_update_dpp((int)lo, (int)lo, CTRL, 0xF, 0xF, false);
    hi = (unsigned)__builtin_amdgcn_update_dpp((int)hi, (int)hi, CTRL, 0xF, 0xF, false);
    return ((unsigned long long)hi << 32) | lo;
}

__device__ __forceinline__ unsigned long long wave_max_u64(unsigned long long k) {
    unsigned long long o;
    o = dpp_u64<0x111>(k); if (o > k) k = o;   // row_shr:1
    o = dpp_u64<0x112>(k); if (o > k) k = o;   // row_shr:2
    o = dpp_u64<0x114>(k); if (o > k) k = o;   // row_shr:4
    o = dpp_u64<0x118>(k); if (o > k) k = o;   // row_shr:8
    o = dpp_u64<0x142>(k); if (o > k) k = o;   // row_bcast:15
    o = dpp_u64<0x143>(k); if (o > k) k = o;   // row_bcast:31
    return k;
}

__device__ __forceinline__ unsigned long long wave_min_u64(unsigned long long k) {
    unsigned long long o;
    o = dpp_u64<0x111>(k); if (o < k) k = o;
    o = dpp_u64<0x112>(k); if (o < k) k = o;
    o = dpp_u64<0x114>(k); if (o < k) k = o;
    o = dpp_u64<0x118>(k); if (o < k) k = o;
    o = dpp_u64<0x142>(k); if (o < k) k = o;
    o = dpp_u64<0x143>(k); if (o < k) k = o;
    return k;
}

// Tree-min over a 16-entry register array (static indices after inlining).
__device__ __forceinline__ unsigned long long min16_u64(const unsigned long long* k) {
    unsigned long long t8[8];
#pragma unroll
    for (int i = 0; i < 8; ++i) t8[i] = k[i] < k[i + 8] ? k[i] : k[i + 8];
    unsigned long long t4[4];
#pragma unroll
    for (int i = 0; i < 4; ++i) t4[i] = t8[i] < t8[i + 4] ? t8[i] : t8[i + 4];
    unsigned long long a = t4[0] < t4[2] ? t4[0] : t4[2];
    unsigned long long b = t4[1] < t4[3] ? t4[1] : t4[3];
    return a < b ? a : b;
}

// ---------------------------------------------------------------------------
// Init kernel: zero the per-batch progress counters.
// ---------------------------------------------------------------------------
__global__ void init_progress(int* progress) {
    if (threadIdx.x < BATCH)
        __hip_atomic_store(&progress[threadIdx.x], 0,
                           __ATOMIC_RELAXED, __HIP_MEMORY_SCOPE_AGENT);
}

// ---------------------------------------------------------------------------
// Merged producer-consumer kernel.
//   blocks [0,16):        FPS producer (512 thr), s_setprio(3), batched
//                         publication every 8 centers.
//   blocks [16,16+8192):  consumer per (g,b), exact 32-NN + gather.
// ---------------------------------------------------------------------------
__global__ __launch_bounds__(512) void group_kernel(const float* __restrict__ xyz,
                                                    const float* __restrict__ features,
                                                    float* __restrict__ out0,
                                                    float* __restrict__ out1,
                                                    float* __restrict__ out2,
                                                    int* __restrict__ progress) {
#pragma clang fp contract(off)
    __shared__ unsigned long long sk[2][8];   // per-wave reduce slots (both roles)
    __shared__ int   sidx[KM];                // consumer: knn result indices
    __shared__ float scst[24];                // producer: center stash / consumer: sc

    const int tid  = threadIdx.x;
    const int lane = tid & 63;
    const int wid  = tid >> 6;                // 8 waves

    if (blockIdx.x < BATCH) {
        // ================= FPS producer =================
        __builtin_amdgcn_s_setprio(3);        // win SIMD arbitration vs consumers
        const int b = blockIdx.x;
        const float* xb = xyz + (size_t)b * NPTS * 3;
        float* co = out1 + (size_t)b * NG * 3;

        // 16 points per thread as 8 packed pairs (one-time global load).
        f32x2 X[8], Y[8], Z[8], MD[8];
#pragma unroll
        for (int j = 0; j < 8; ++j) {
            int p0 = tid + 1024 * j;
            int p1 = p0 + 512;
            X[j]  = (f32x2){xb[p0 * 3 + 0], xb[p1 * 3 + 0]};
            Y[j]  = (f32x2){xb[p0 * 3 + 1], xb[p1 * 3 + 1]};
            Z[j]  = (f32x2){xb[p0 * 3 + 2], xb[p1 * 3 + 2]};
            MD[j] = (f32x2){1e10f, 1e10f};
        }

        int far = 0;
        for (int g = 0; g < NG; ++g) {
            // Broadcast load of the current center's coords (same addr all lanes).
            const float cx = xb[far * 3 + 0];
            const float cy = xb[far * 3 + 1];
            const float cz = xb[far * 3 + 2];
            if (tid == 0) {                   // stash for batched publication
                scst[(g & 7) * 3 + 0] = cx;
                scst[(g & 7) * 3 + 1] = cy;
                scst[(g & 7) * 3 + 2] = cz;
            }
            const f32x2 cx2 = (f32x2){cx, cx};
            const f32x2 cy2 = (f32x2){cy, cy};
            const f32x2 cz2 = (f32x2){cz, cz};

            // Exact min-dist update: ((dx*dx + dy*dy) + dz*dz), no fma.
#pragma unroll
            for (int j = 0; j < 8; ++j) {
                f32x2 dx = X[j] - cx2;
                f32x2 dy = Y[j] - cy2;
                f32x2 dz = Z[j] - cz2;
                f32x2 d  = (dx * dx + dy * dy) + dz * dz;
                MD[j] = __builtin_elementwise_min(MD[j], d);
            }
            // Per-lane max value.
            f32x2 a0 = __builtin_elementwise_max(MD[0], MD[1]);
            f32x2 a1 = __builtin_elementwise_max(MD[2], MD[3]);
            f32x2 a2 = __builtin_elementwise_max(MD[4], MD[5]);
            f32x2 a3 = __builtin_elementwise_max(MD[6], MD[7]);
            f32x2 b0 = __builtin_elementwise_max(a0, a1);
            f32x2 b1 = __builtin_elementwise_max(a2, a3);
            f32x2 c0 = __builtin_elementwise_max(b0, b1);
            float lmax = fmaxf(c0.x, c0.y);

            // Smallest owned index attaining lmax.
            unsigned candX = 0xFFFFFFFFu, candY = 0xFFFFFFFFu;
#pragma unroll
            for (int j = 7; j >= 0; --j) {
                if (MD[j].y == lmax) candY = (unsigned)(tid + 1024 * j + 512);
                if (MD[j].x == lmax) candX = (unsigned)(tid + 1024 * j);
            }
            unsigned cand = candX < candY ? candX : candY;

            unsigned long long key =
                ((unsigned long long)__float_as_uint(lmax) << 32) | (unsigned)(~cand);
            key = wave_max_u64(key);          // lane 63 valid

            const int par = g & 1;
            if (lane == 63) sk[par][wid] = key;
            __syncthreads();

            unsigned long long m0 = sk[par][0] > sk[par][1] ? sk[par][0] : sk[par][1];
            unsigned long long m1 = sk[par][2] > sk[par][3] ? sk[par][2] : sk[par][3];
            unsigned long long m2 = sk[par][4] > sk[par][5] ? sk[par][4] : sk[par][5];
            unsigned long long m3 = sk[par][6] > sk[par][7] ? sk[par][6] : sk[par][7];
            unsigned long long ma = m0 > m1 ? m0 : m1;
            unsigned long long mb = m2 > m3 ? m2 : m3;
            unsigned long long gk = ma > mb ? ma : mb;
            far = (int)(~(unsigned)gk);

            // Batched publication: 8 centers + progress, wave 0 only.
            if ((g & 7) == 7) {
                if (tid < 24) co[(g - 7) * 3 + tid] = scst[tid];
                if (tid == 0)
                    __hip_atomic_store(&progress[b], g + 1,
                                       __ATOMIC_RELEASE, __HIP_MEMORY_SCOPE_AGENT);
            }
        }
        return;
    }

    // ================= consumer: KNN + gather for one (b,g) =================
    const int i = blockIdx.x - BATCH;
    const int b = i & 15;              // g-major: matches production order
    const int g = i >> 4;
    const int bgrow = b * NG + g;

    if (tid == 0) {
        while ((int)__hip_atomic_load(&progress[b], __ATOMIC_ACQUIRE,
                                      __HIP_MEMORY_SCOPE_AGENT) < g + 1)
            __builtin_amdgcn_s_sleep(32);
        unsigned* co = (unsigned*)out1 + (size_t)bgrow * 3;
        scst[0] = __uint_as_float(__hip_atomic_load(co + 0, __ATOMIC_RELAXED,
                                                    __HIP_MEMORY_SCOPE_AGENT));
        scst[1] = __uint_as_float(__hip_atomic_load(co + 1, __ATOMIC_RELAXED,
                                                    __HIP_MEMORY_SCOPE_AGENT));
        scst[2] = __uint_as_float(__hip_atomic_load(co + 2, __ATOMIC_RELAXED,
                                                    __HIP_MEMORY_SCOPE_AGENT));
    }
    __syncthreads();

    const float cx = scst[0], cy = scst[1], cz = scst[2];
    const float q2 = (cx * cx + cy * cy) + cz * cz;   // plain add chain

    const float* xb = xyz + (size_t)b * NPTS * 3;

    // Exact distances for 16 points/thread, packed sortable u64 keys.
    unsigned long long k[16];
#pragma unroll
    for (int j = 0; j < 16; ++j) {
        int p = tid + (j << 9);
        float rx = xb[p * 3 + 0];
        float ry = xb[p * 3 + 1];
        float rz = xb[p * 3 + 2];
        float r2 = (rx * rx + ry * ry) + rz * rz;         // plain add chain
        float dot = fmaf(cz, rz, fmaf(cy, ry, cx * rx));  // fma chain (sgemm-style)
        float d = (q2 + r2) - 2.0f * dot;                 // identical to round 1
        unsigned u = __float_as_uint(d);
        u ^= ((unsigned)((int)u >> 31)) | 0x80000000u;    // sortable float
        k[j] = ((unsigned long long)u << 32) | (unsigned)p;
    }

    unsigned long long lv = min16_u64(k);
    // Per-wave cached min: lane 63 keeps wkey; LDS slots parity-double-buffered.
    unsigned long long wkey = wave_min_u64(lv);           // lane 63 valid
    if (lane == 63) sk[0][wid] = wkey;
    __syncthreads();

    for (int kk = 0; kk < KM; ++kk) {
        const int par = kk & 1;
        const int nxt = par ^ 1;
        // All threads: tree-min over the 8 cached wave keys.
        unsigned long long m0 = sk[par][0] < sk[par][1] ? sk[par][0] : sk[par][1];
        unsigned long long m1 = sk[par][2] < sk[par][3] ? sk[par][2] : sk[par][3];
        unsigned long long m2 = sk[par][4] < sk[par][5] ? sk[par][4] : sk[par][5];
        unsigned long long m3 = sk[par][6] < sk[par][7] ? sk[par][6] : sk[par][7];
        unsigned long long ma = m0 < m1 ? m0 : m1;
        unsigned long long mb = m2 < m3 ? m2 : m3;
        unsigned long long gk = ma < mb ? ma : mb;
        const unsigned pt = (unsigned)gk;                 // low 32 = point idx
        const int wwave = (int)((pt & 511u) >> 6);

        if (wid == wwave) {
            // Only the winning wave recomputes its reduction.
            if ((pt & 511u) == (unsigned)tid) {
                sidx[kk] = (int)pt;
                const unsigned jw = pt >> 9;
#pragma unroll
                for (int j = 0; j < 16; ++j) {
                    if ((unsigned)j == jw) k[j] = ~0ULL;
                }
                lv = min16_u64(k);
            }
            wkey = wave_min_u64(lv);
            if (lane == 63) sk[nxt][wid] = wkey;
        } else {
            if (lane == 63) sk[nxt][wid] = wkey;          // re-publish cached key
        }
        __syncthreads();
    }

    // neighborhood: 32 x 3 = 96 floats (exact plain subtract).
    if (tid < 96) {
        int m = tid / 3;
        int c = tid - 3 * m;
        int p = sidx[m];
        float v = xb[p * 3 + c] - scst[c];
        out0[((size_t)bgrow * KM + m) * 3 + c] = v;
    }

    // features: 32 rows x 96 float4 = 3072 float4, 6 per thread.
    const float4* fb = (const float4*)(features + (size_t)b * NPTS * FEATC);
    float4*       ob = (float4*)(out2 + (size_t)bgrow * KM * FEATC);
#pragma unroll
    for (int r = 0; r < 6; ++r) {
        int flat = tid + (r << 9);          // 0..3071
        int m  = flat / 96;
        int c4 = flat - 96 * m;
        float4 v = fb[(size_t)sidx[m] * 96 + c4];
        ob[(size_t)m * 96 + c4] = v;
    }
}

extern "C" void kernel_launch(void* const* d_in, const int* in_sizes, int n_in,
                              void* d_out, int out_size, void* d_ws, size_t ws_size,
                              hipStream_t stream) {
    const float* xyz      = (const float*)d_in[0];
    const float* features = (const float*)d_in[1];
    float* out  = (float*)d_out;
    float* out0 = out + OUT0_OFF;   // neighborhood
    float* out1 = out + OUT1_OFF;   // center
    float* out2 = out + OUT2_OFF;   // feature_group

    int* progress = (int*)d_ws;     // 16 ints

    init_progress<<<1, 64, 0, stream>>>(progress);
    group_kernel<<<BATCH + BATCH * NG, 512, 0, stream>>>(xyz, features,
                                                         out0, out1, out2,
                                                         progress);
}